// Round 7
// baseline (281.310 us; speedup 1.0000x reference)
//
#include <hip/hip_runtime.h>
#include <stdint.h>

// Problem constants
#define BB 2
#define SS 2048
#define HIDD 2048
#define HH 16
#define KVH 4
#define DD 128
#define KDIM 2048

typedef short bf16x4 __attribute__((ext_vector_type(4)));
typedef short bf16x8 __attribute__((ext_vector_type(8)));
typedef float f32x4 __attribute__((ext_vector_type(4)));
typedef float f32x16 __attribute__((ext_vector_type(16)));

__device__ __forceinline__ unsigned short f2b(float f) {
  union { float f; unsigned u; } v; v.f = f;
  unsigned r = v.u + 0x7FFFu + ((v.u >> 16) & 1u);
  return (unsigned short)(r >> 16);
}

__device__ __forceinline__ float b2f(unsigned short u) {
  union { unsigned u; float f; } v; v.u = ((unsigned)u) << 16;
  return v.f;
}

__device__ __forceinline__ unsigned cvtpk_bf16(float a, float b) {
  unsigned r;
  asm("v_cvt_pk_bf16_f32 %0, %1, %2" : "=v"(r) : "v"(a), "v"(b));
  return r;
}

// async global->LDS, 16B per lane; LDS dest is wave-uniform base + lane*16
__device__ __forceinline__ void gload16(const unsigned short* g, unsigned short* l) {
  __builtin_amdgcn_global_load_lds(
      (const __attribute__((address_space(1))) unsigned int*)(g),
      (__attribute__((address_space(3))) unsigned int*)(l), 16, 0, 0);
}

// 16B LDS tile read
__device__ __forceinline__ bf16x8 ldT(const char* lds, int byteoff) {
  union { bf16x8 v; int4 q; } u;
  u.q = *reinterpret_cast<const int4*>(lds + byteoff);
  return u.v;
}

// A/B-fragment interleave within a 16-elem group: element x stored at
// pos16(x) = (x&3) | ((x&4)<<1) | ((x&8)>>1); then a contiguous 16B chunk
// (8 elems) holds x = base + {0,1,2,3,8,9,10,11} — the MFMA fragment order.

// K-dim interleave perm within 32-elem blocks (for 16x16x32 GEMM frags):
// perm(k32) = ((k32>>2)&3)*8 + (k32&3) + ((k32>>4)<<2)

__global__ __launch_bounds__(256) void k_convert(const float* __restrict__ in,
                                                 unsigned short* __restrict__ out, int n4) {
  int i = blockIdx.x * 256 + threadIdx.x;
  int stride = gridDim.x * 256;
  for (; i < n4; i += stride) {
    float4 v = reinterpret_cast<const float4*>(in)[i];
    ushort4 o;
    o.x = f2b(v.x); o.y = f2b(v.y); o.z = f2b(v.z); o.w = f2b(v.w);
    int ci = i & 511;
    int t = ci & 7;
    int ci2 = (ci & ~7) | ((t & 3) << 1) | (t >> 2);
    reinterpret_cast<ushort4*>(out)[(i & ~511) | ci2] = o;
  }
}

// in: (K,N) fp32 row-major -> out: (N,K) bf16 row-major with K-dim interleave perm
__global__ __launch_bounds__(256) void k_transpose(const float* __restrict__ in,
                                                   unsigned short* __restrict__ out,
                                                   int K, int N) {
  __shared__ float tile[32][33];
  int n0 = blockIdx.x * 32, k0 = blockIdx.y * 32;
  int tx = threadIdx.x, ty = threadIdx.y;
#pragma unroll
  for (int j = 0; j < 32; j += 8)
    tile[ty + j][tx] = in[(size_t)(k0 + ty + j) * N + n0 + tx];
  __syncthreads();
  int kp = ((tx >> 2) & 3) * 8 + (tx & 3) + ((tx >> 4) << 2);
#pragma unroll
  for (int j = 0; j < 32; j += 8)
    out[(size_t)(n0 + ty + j) * K + k0 + kp] = f2b(tile[tx][ty + j]);
}

// C = A(M x K) * Bt(N x K)^T, bf16 (K-dim pre-interleaved), 128x128 tile, 4 waves.
template <int EPI>
__global__ __launch_bounds__(256) void k_gemm(
    const unsigned short* __restrict__ A, const unsigned short* __restrict__ Bt,
    float* __restrict__ outF, unsigned short* __restrict__ qws,
    unsigned short* __restrict__ kws, unsigned short* __restrict__ vTws,
    float* __restrict__ koutF, float* __restrict__ voutF,
    const float* __restrict__ cosT, const float* __restrict__ sinT) {
  __shared__ __align__(16) unsigned short lA[2][128 * 32];
  __shared__ __align__(16) unsigned short lB[2][128 * 32];
  const int rowbase = blockIdx.x * 128;
  const int colbase = blockIdx.y * 128;
  const int t = threadIdx.x;
  const int wid = t >> 6, lane = t & 63;
  const int g = lane >> 4, c = lane & 15;
  const int wrow = (wid >> 1) * 64, wcol = (wid & 1) * 64;

  const int rloc = lane >> 2, sslot = lane & 3;

  f32x4 acc[4][4] = {};

  const int NT = KDIM / 32;

  auto STAGE = [&](int buf, int kt) {
    const int kbase = kt * 32;
#pragma unroll
    for (int j = 0; j < 2; ++j) {
      int r = wid * 32 + j * 16 + rloc;
      int gch = sslot ^ ((r >> 1) & 3);
      gload16(A + (size_t)(rowbase + r) * KDIM + kbase + gch * 8,
              &lA[buf][(wid * 32 + j * 16) * 32]);
      gload16(Bt + (size_t)(colbase + r) * KDIM + kbase + gch * 8,
              &lB[buf][(wid * 32 + j * 16) * 32]);
    }
  };

  STAGE(0, 0);
  __syncthreads();

  for (int kt = 0; kt < NT; ++kt) {
    const int cur = kt & 1;
    if (kt + 1 < NT) STAGE(cur ^ 1, kt + 1);

    const unsigned short* la = lA[cur];
    const unsigned short* lb = lB[cur];
    bf16x8 af[4], bfm[4];
#pragma unroll
    for (int m = 0; m < 4; ++m) {
      int r = wrow + m * 16 + c;
      int slot = g ^ ((r >> 1) & 3);
      af[m] = *reinterpret_cast<const bf16x8*>(la + r * 32 + slot * 8);
    }
#pragma unroll
    for (int n = 0; n < 4; ++n) {
      int r = wcol + n * 16 + c;
      int slot = g ^ ((r >> 1) & 3);
      bfm[n] = *reinterpret_cast<const bf16x8*>(lb + r * 32 + slot * 8);
    }
#pragma unroll
    for (int m = 0; m < 4; ++m)
#pragma unroll
      for (int n = 0; n < 4; ++n)
        acc[m][n] = __builtin_amdgcn_mfma_f32_16x16x32_bf16(af[m], bfm[n], acc[m][n], 0, 0, 0);
    __syncthreads();
  }

  if (EPI == 0) {
#pragma unroll
    for (int m = 0; m < 4; ++m)
#pragma unroll
      for (int n = 0; n < 4; ++n)
#pragma unroll
        for (int i = 0; i < 4; ++i) {
          int R = rowbase + wrow + m * 16 + g * 4 + i;
          int Cc = colbase + wcol + n * 16 + c;
          outF[(size_t)R * 2048 + Cc] = acc[m][n][i];
        }
  } else {
#pragma unroll
    for (int m = 0; m < 4; ++m) {
#pragma unroll
      for (int n = 0; n < 4; ++n) {
#pragma unroll
        for (int i = 0; i < 4; ++i) {
          float val = acc[m][n][i];
          float partner = __shfl_xor(val, 1, 64);
          int R = rowbase + wrow + m * 16 + g * 4 + i;
          int Cc = colbase + wcol + n * 16 + c;
          int b = R >> 11, s = R & 2047;
          int d = Cc & 127;
          int j = d >> 1;
          float cs = cosT[s * 64 + j], sn = sinT[s * 64 + j];
          float ro = ((d & 1) == 0) ? (val * cs - partner * sn)
                                    : (partner * sn + val * cs);
          if (Cc < 2048) {
            int h = Cc >> 7;
            qws[((size_t)(b * HH + h) * SS + s) * DD + d] = f2b(ro);
          } else if (Cc < 2560) {
            int kvh = (Cc - 2048) >> 7;
            size_t idx = ((size_t)(b * KVH + kvh) * SS + s) * DD + d;
            koutF[idx] = ro;
            // kws: d pre-interleaved within 16-groups for k_attn's A-frag staging
            int d16 = d & 15;
            int dp = (d & ~15) | (d16 & 3) | ((d16 & 4) << 1) | ((d16 & 8) >> 1);
            kws[((size_t)(b * KVH + kvh) * SS + s) * DD + dp] = f2b(ro);
          } else {
            int kvh = (Cc - 2560) >> 7;
            size_t idx = ((size_t)(b * KVH + kvh) * SS + s) * DD + d;
            voutF[idx] = val;
            // vTws: s pre-interleaved within 16-groups for k_attn's A-frag staging
            int s16 = s & 15;
            int sp = (s & ~15) | (s16 & 3) | ((s16 & 4) << 1) | ((s16 & 8) >> 1);
            vTws[((size_t)(b * KVH + kvh) * DD + d) * SS + sp] = f2b(val);
          }
        }
      }
    }
  }
}

// LPT job table: 24 jobs/head sorted by tile count desc.
// full chunks c=0..7 (NT=2c+2); split chunks c=8..15 as two KV-halves (NT=c+1 each).
__constant__ int JC[24] = {7,15,15,14,14,6,13,13,12,12,5,11,11,10,10,4,9,9,8,8,3,2,1,0};
__constant__ int JP[24] = {0,0,1, 0,1, 0,0,1, 0,1, 0,0,1, 0,1, 0,0,1, 0,1, 0,0,0,0};

// Flash attention, 32x32 MFMA, double-swapped operands.
// K/V staged via global_load_lds into subtiled conflict-free LDS layouts:
//   K[ks(8)][half(2)][lq(32)][hi(2)] 16B chunks (16KB), V[kk(4)][d0(4)][lq][hi] (16KB),
// double-buffered (64KB). Counted vmcnt(8) pipeline, raw s_barriers (T3/T4).
// kws/vTws are pre-interleaved so each 16B chunk is a ready A-fragment.
// Chunks>=8 split into two KV-halves writing (m,l,O) partials (flash-decoding).
__global__ __launch_bounds__(256, 2) void k_attn(const unsigned short* __restrict__ qws,
                                                 const unsigned short* __restrict__ kws,
                                                 const unsigned short* __restrict__ vT,
                                                 unsigned short* __restrict__ aows,
                                                 unsigned short* __restrict__ pO,
                                                 float* __restrict__ pml) {
  __shared__ __align__(16) char lds[2][32768];  // per buf: K 16KB | V 16KB
  const int tid = threadIdx.x;
  const int lane = tid & 63;
  const int w = tid >> 6;
  const int lq = lane & 31;   // this lane's q-column
  const int hi = lane >> 5;   // k-parity half

  const int bid = blockIdx.x;
  const int j = bid >> 5;                           // job id (LPT order)
  const int y = bid & 31;
  const int head = 4 * (y & 7) + ((y >> 3) & 3);    // one (b,kv) per XCD
  const int c = JC[j];
  const int part = JP[j];
  const bool split = (c >= 8);
  const int tstart = split ? (part ? (c + 1) : 0) : 0;
  const int tend = split ? (part ? (2 * c + 2) : (c + 1)) : (2 * c + 2);

  const int b = head >> 4, h = head & 15;
  const int kv = h >> 2;
  const int q0w = c * 128 + w * 32;
  const int qg = q0w + lq;
  const float cl2 = 0.12751743f;  // (1/sqrt(128)) * log2(e)

  const unsigned short* qp = qws + ((size_t)(b * HH + h) * SS + qg) * DD;
  bf16x8 qf[8];
#pragma unroll
  for (int ks = 0; ks < 8; ++ks) {
    union { bf16x8 v8; bf16x4 v4[2]; } u;
    const unsigned short* p = qp + ks * 16 + hi * 4;
    u.v4[0] = *reinterpret_cast<const bf16x4*>(p);
    u.v4[1] = *reinterpret_cast<const bf16x4*>(p + 8);
    qf[ks] = u.v8;
  }

  const unsigned short* kbase = kws + (size_t)(b * KVH + kv) * SS * DD;
  const unsigned short* vbase = vT + (size_t)(b * KVH + kv) * DD * SS;

  // per-lane staging sources: wave w handles instrs i = w + 4*j2, j2=0..3
  const unsigned short* kSrc[4];
  const unsigned short* vSrc[4];
  int ldsOff[4];
#pragma unroll
  for (int j2 = 0; j2 < 4; ++j2) {
    int i = w + 4 * j2;
    int ks = i >> 1, half = i & 1;
    kSrc[j2] = kbase + (size_t)(half * 32 + (lane >> 1)) * DD + ks * 16 + (lane & 1) * 8;
    int kkv = i >> 2, d0v = i & 3;
    vSrc[j2] = vbase + (size_t)(d0v * 32 + (lane >> 1)) * SS + kkv * 16 + (lane & 1) * 8;
    ldsOff[j2] = i * 1024;
  }

  auto STAGE = [&](int t, int buf) {
    char* lK = lds[buf];
    char* lV = lds[buf] + 16384;
#pragma unroll
    for (int j2 = 0; j2 < 4; ++j2) {
      gload16(kSrc[j2] + (size_t)t * 64 * DD, (unsigned short*)(lK + ldsOff[j2]));
      gload16(vSrc[j2] + (size_t)t * 64, (unsigned short*)(lV + ldsOff[j2]));
    }
  };

  f32x16 o[4] = {};
  float mrow = -1e30f, lrow = 0.f;

  // prologue: two tiles in flight
  STAGE(tstart, 0);
  STAGE(tstart + 1, 1);
  asm volatile("s_waitcnt vmcnt(8)" ::: "memory");
  __builtin_amdgcn_sched_barrier(0);
  __builtin_amdgcn_s_barrier();

  for (int t = tstart; t < tend; ++t) {
    const int cur = (t - tstart) & 1;

    if (t * 64 <= q0w + 31) {  // wave has live rows in this tile
      const char* lK = lds[cur];
      const char* lV = lds[cur] + 16384;
      const bool full2 = (t * 64 + 32 <= q0w + 31);

      f32x16 s0 = {}, s1 = {};
      __builtin_amdgcn_s_setprio(1);
#pragma unroll
      for (int ks = 0; ks < 8; ++ks) {
        int off = ks * 2048 + lq * 32 + hi * 16;
        s0 = __builtin_amdgcn_mfma_f32_32x32x16_bf16(ldT(lK, off), qf[ks], s0, 0, 0, 0);
      }
      if (full2) {
#pragma unroll
        for (int ks = 0; ks < 8; ++ks) {
          int off = ks * 2048 + 1024 + lq * 32 + hi * 16;
          s1 = __builtin_amdgcn_mfma_f32_32x32x16_bf16(ldT(lK, off), qf[ks], s1, 0, 0, 0);
        }
      }
      __builtin_amdgcn_s_setprio(0);

      // softmax (log2 domain); k = t*64 + half*32 + (r&3)+8*(r>>2)+4*hi
      const int kq = t * 64 + 4 * hi - qg;
      float p[32];
      float rowmax = -1e30f;
      const bool m0 = (t * 64 + 31) > q0w;
#pragma unroll
      for (int r = 0; r < 16; ++r) {
        float v = s0[r] * cl2;
        if (m0) {
          int kl = (r & 3) + 8 * (r >> 2);
          if (kq + kl > 0) v = -1e30f;
        }
        p[r] = v;
        rowmax = fmaxf(rowmax, v);
      }
      if (full2) {
        const bool m1 = (t * 64 + 63) > q0w;
#pragma unroll
        for (int r = 0; r < 16; ++r) {
          float v = s1[r] * cl2;
          if (m1) {
            int kl = 32 + (r & 3) + 8 * (r >> 2);
            if (kq + kl > 0) v = -1e30f;
          }
          p[16 + r] = v;
          rowmax = fmaxf(rowmax, v);
        }
      }
      rowmax = fmaxf(rowmax, __shfl_xor(rowmax, 32, 64));

      if (__any(rowmax > mrow + 8.f)) {  // T13 defer-max
        float mnew = fmaxf(mrow, rowmax);
        float fac = exp2f(mrow - mnew);
        mrow = mnew;
        lrow *= fac;
#pragma unroll
        for (int d0 = 0; d0 < 4; ++d0)
#pragma unroll
          for (int r = 0; r < 16; ++r) o[d0][r] *= fac;
      }

      float rsum = 0.f;
#pragma unroll
      for (int e = 0; e < 16; ++e) { p[e] = exp2f(p[e] - mrow); rsum += p[e]; }
      if (full2) {
#pragma unroll
        for (int e = 16; e < 32; ++e) { p[e] = exp2f(p[e] - mrow); rsum += p[e]; }
      }
      rsum += __shfl_xor(rsum, 32, 64);
      lrow += rsum;

      bf16x8 pf[4];
#pragma unroll
      for (int s4 = 0; s4 < 2; ++s4) {
        union { bf16x8 v; unsigned u[4]; } pu;
        int base = s4 * 8;
#pragma unroll
        for (int jj = 0; jj < 4; ++jj)
          pu.u[jj] = cvtpk_bf16(p[base + 2 * jj], p[base + 2 * jj + 1]);
        pf[s4] = pu.v;
      }
      if (full2) {
#pragma unroll
        for (int s4 = 2; s4 < 4; ++s4) {
          union { bf16x8 v; unsigned u[4]; } pu;
          int base = 16 + (s4 - 2) * 8;
#pragma unroll
          for (int jj = 0; jj < 4; ++jj)
            pu.u[jj] = cvtpk_bf16(p[base + 2 * jj], p[base + 2 * jj + 1]);
          pf[s4] = pu.v;
        }
      }

      __builtin_amdgcn_s_setprio(1);
#pragma unroll
      for (int d0 = 0; d0 < 4; ++d0)
#pragma unroll
        for (int kk = 0; kk < 2; ++kk) {
          int off = (kk * 4 + d0) * 1024 + lq * 32 + hi * 16;
          o[d0] = __builtin_amdgcn_mfma_f32_32x32x16_bf16(ldT(lV, off), pf[kk], o[d0], 0, 0, 0);
        }
      if (full2) {
#pragma unroll
        for (int d0 = 0; d0 < 4; ++d0)
#pragma unroll
          for (int kk = 2; kk < 4; ++kk) {
            int off = (kk * 4 + d0) * 1024 + lq * 32 + hi * 16;
            o[d0] = __builtin_amdgcn_mfma_f32_32x32x16_bf16(ldT(lV, off), pf[kk], o[d0], 0, 0, 0);
          }
      }
      __builtin_amdgcn_s_setprio(0);
    }

    if (t + 1 < tend) {
      __builtin_amdgcn_s_barrier();           // all waves done reading buf[cur]
      if (t + 2 < tend) {
        STAGE(t + 2, cur);                    // overwrite buf[cur] (readers done)
        asm volatile("s_waitcnt vmcnt(8)" ::: "memory");  // t+1 landed; t+2 in flight
      } else {
        asm volatile("s_waitcnt vmcnt(0)" ::: "memory");  // t+1 landed
      }
      __builtin_amdgcn_sched_barrier(0);
      __builtin_amdgcn_s_barrier();           // publish t+1
    }
  }

  if (!split) {
    // normalize + store with K-dim interleave perm for GEMM2.
    float linv = 1.f / lrow;
    unsigned short* op = aows + ((size_t)(b * SS + qg)) * 2048 + h * 128;
#pragma unroll
    for (int d0 = 0; d0 < 4; ++d0)
#pragma unroll
      for (int rq = 0; rq < 4; ++rq) {
        unsigned w0 = cvtpk_bf16(o[d0][rq * 4 + 0] * linv, o[d0][rq * 4 + 1] * linv);
        unsigned w1 = cvtpk_bf16(o[d0][rq * 4 + 2] * linv, o[d0][rq * 4 + 3] * linv);
        int2 st2; st2.x = (int)w0; st2.y = (int)w1;
        int pos = 8 * ((2 * rq + hi) & 3) + 4 * (rq >> 1);
        *reinterpret_cast<int2*>(op + d0 * 32 + pos) = st2;
      }
  } else {
    // store unnormalized partial (plain d layout) + m,l
    int c8 = c - 8;
    int row = qg - c * 128;
    unsigned short* op = pO + ((((size_t)(head * 8 + c8) * 2 + part) * 128) + row) * 128;
#pragma unroll
    for (int d0 = 0; d0 < 4; ++d0)
#pragma unroll
      for (int rq = 0; rq < 4; ++rq) {
        unsigned w0 = cvtpk_bf16(o[d0][rq * 4 + 0], o[d0][rq * 4 + 1]);
        unsigned w1 = cvtpk_bf16(o[d0][rq * 4 + 2], o[d0][rq * 4 + 3]);
        int2 st2; st2.x = (int)w0; st2.y = (int)w1;
        *reinterpret_cast<int2*>(op + d0 * 32 + rq * 8 + hi * 4) = st2;
      }
    if (hi == 0) {
      int mlbase = (((head * 8 + c8) * 2 + part) * 2) * 128 + row;
      pml[mlbase] = mrow;
      pml[mlbase + 128] = lrow;
    }
  }
}

// Combine two KV-half partials for chunks 8..15 and write aows (perm'd bf16).
__global__ __launch_bounds__(256) void k_combine(const unsigned short* __restrict__ pO,
                                                 const float* __restrict__ pml,
                                                 unsigned short* __restrict__ aows) {
  int tid = blockIdx.x * 256 + threadIdx.x;  // 524288 total
  int rg = tid >> 4;
  int d8 = tid & 15;
  int head = rg >> 10;
  int rem = rg & 1023;
  int c8 = rem >> 7;
  int row = rem & 127;
  int base2 = (head * 8 + c8) * 2;

  float m1 = pml[((base2 + 0) * 2 + 0) * 128 + row];
  float l1 = pml[((base2 + 0) * 2 + 1) * 128 + row];
  float m2 = pml[((base2 + 1) * 2 + 0) * 128 + row];
  float l2 = pml[((base2 + 1) * 2 + 1) * 128 + row];
  float m = fmaxf(m1, m2);
  float w1 = exp2f(m1 - m), w2 = exp2f(m2 - m);
  float inv = 1.f / (w1 * l1 + w2 * l2);

  const unsigned short* o1 = pO + (((size_t)(base2 + 0) * 128 + row) * 128) + d8 * 8;
  const unsigned short* o2 = pO + (((size_t)(base2 + 1) * 128 + row) * 128) + d8 * 8;
  union { int4 q; unsigned short us[8]; } ua, ub;
  ua.q = *reinterpret_cast<const int4*>(o1);
  ub.q = *reinterpret_cast<const int4*>(o2);
  float out[8];
#pragma unroll
  for (int e = 0; e < 8; ++e)
    out[e] = (w1 * b2f(ua.us[e]) + w2 * b2f(ub.us[e])) * inv;

  int b = head >> 4, h = head & 15;
  int s = (c8 + 8) * 128 + row;
  unsigned short* dst = aows + ((size_t)(b * SS + s)) * 2048 + h * 128;
  int d = d8 * 8;
  int dbase = d & ~31;
#pragma unroll
  for (int jj = 0; jj < 2; ++jj) {
    int t = ((d >> 2) + jj) & 7;
    int pos = ((t & 3) << 3) + ((t >> 2) << 2);
    unsigned wa = cvtpk_bf16(out[jj * 4 + 0], out[jj * 4 + 1]);
    unsigned wb = cvtpk_bf16(out[jj * 4 + 2], out[jj * 4 + 3]);
    int2 st2; st2.x = (int)wa; st2.y = (int)wb;
    *reinterpret_cast<int2*>(dst + dbase + pos) = st2;
  }
}

extern "C" void kernel_launch(void* const* d_in, const int* in_sizes, int n_in,
                              void* d_out, int out_size, void* d_ws, size_t ws_size,
                              hipStream_t stream) {
  (void)in_sizes; (void)n_in; (void)out_size; (void)ws_size;
  const float* x  = (const float*)d_in[0];
  const float* fc = (const float*)d_in[1];
  const float* fs = (const float*)d_in[2];
  const float* wq = (const float*)d_in[3];
  const float* wk = (const float*)d_in[4];
  const float* wv = (const float*)d_in[5];
  const float* wo = (const float*)d_in[6];
  float* out = (float*)d_out;
  float* koutF = out + (size_t)BB * SS * HIDD;                  // (B,KV,S,D)
  float* voutF = koutF + (size_t)BB * KVH * SS * DD;            // (B,KV,S,D)

  unsigned short* wcatT = (unsigned short*)d_ws;                // (3072, 2048)
  unsigned short* woT   = wcatT + (size_t)3072 * 2048;          // (2048, 2048)
  unsigned short* xbf   = woT + (size_t)2048 * 2048;            // (4096, 2048)
  unsigned short* qws   = xbf + (size_t)4096 * 2048;            // (B,H,S,D)
  unsigned short* kws   = qws + (size_t)BB * HH * SS * DD;      // (B,KV,S,D) d-interleaved
  unsigned short* vTws  = kws + (size_t)BB * KVH * SS * DD;     // (B,KV,D,S) s-interleaved
  unsigned short* aows  = vTws + (size_t)BB * KVH * DD * SS;    // (B*S, H*D)

  // partials alias regions dead after k_gemm<1>:
  unsigned short* pO = xbf;            // 32*8*2*128*128 shorts = xbf size exactly
  float* pml = (float*)wcatT;          // 131072 floats << wcatT size

  k_convert<<<2048, 256, 0, stream>>>(x, xbf, (int)((size_t)4096 * 2048 / 4));
  dim3 tb(32, 8);
  k_transpose<<<dim3(64, 64), tb, 0, stream>>>(wq, wcatT, 2048, 2048);
  k_transpose<<<dim3(16, 64), tb, 0, stream>>>(wk, wcatT + (size_t)2048 * 2048, 2048, 512);
  k_transpose<<<dim3(16, 64), tb, 0, stream>>>(wv, wcatT + (size_t)2560 * 2048, 2048, 512);
  k_transpose<<<dim3(64, 64), tb, 0, stream>>>(wo, woT, 2048, 2048);

  k_gemm<1><<<dim3(32, 24), 256, 0, stream>>>(xbf, wcatT, nullptr, qws, kws, vTws,
                                              koutF, voutF, fc, fs);
  k_attn<<<768, 256, 0, stream>>>(qws, kws, vTws, aows, pO, pml);
  k_combine<<<2048, 256, 0, stream>>>(pO, pml, aows);
  k_gemm<0><<<dim3(32, 16), 256, 0, stream>>>(aows, woT, out, nullptr, nullptr, nullptr,
                                              nullptr, nullptr, nullptr, nullptr);
}

// Round 8
// 255.257 us; speedup vs baseline: 1.1021x; 1.1021x over previous
//
#include <hip/hip_runtime.h>
#include <stdint.h>

// Problem constants
#define BB 2
#define SS 2048
#define HIDD 2048
#define HH 16
#define KVH 4
#define DD 128
#define KDIM 2048

typedef short bf16x4 __attribute__((ext_vector_type(4)));
typedef short bf16x8 __attribute__((ext_vector_type(8)));
typedef float f32x4 __attribute__((ext_vector_type(4)));
typedef float f32x16 __attribute__((ext_vector_type(16)));

__device__ __forceinline__ unsigned short f2b(float f) {
  union { float f; unsigned u; } v; v.f = f;
  unsigned r = v.u + 0x7FFFu + ((v.u >> 16) & 1u);
  return (unsigned short)(r >> 16);
}

__device__ __forceinline__ float b2f(unsigned short u) {
  union { unsigned u; float f; } v; v.u = ((unsigned)u) << 16;
  return v.f;
}

__device__ __forceinline__ unsigned cvtpk_bf16(float a, float b) {
  unsigned r;
  asm("v_cvt_pk_bf16_f32 %0, %1, %2" : "=v"(r) : "v"(a), "v"(b));
  return r;
}

// async global->LDS, 16B per lane; LDS dest is wave-uniform base + lane*16
__device__ __forceinline__ void gload16(const unsigned short* g, unsigned short* l) {
  __builtin_amdgcn_global_load_lds(
      (const __attribute__((address_space(1))) unsigned int*)(g),
      (__attribute__((address_space(3))) unsigned int*)(l), 16, 0, 0);
}

// 16B LDS tile read
__device__ __forceinline__ bf16x8 ldT(const char* lds, int byteoff) {
  union { bf16x8 v; int4 q; } u;
  u.q = *reinterpret_cast<const int4*>(lds + byteoff);
  return u.v;
}

// A/B-fragment interleave within a 16-elem group: element x stored at
// pos16(x) = (x&3) | ((x&4)<<1) | ((x&8)>>1); then a contiguous 16B chunk
// (8 elems) holds x = base + {0,1,2,3,8,9,10,11} — the MFMA fragment order.

// K-dim interleave perm within 32-elem blocks (for 16x16x32 GEMM frags):
// perm(k32) = ((k32>>2)&3)*8 + (k32&3) + ((k32>>4)<<2)

__global__ __launch_bounds__(256) void k_convert(const float* __restrict__ in,
                                                 unsigned short* __restrict__ out, int n4) {
  int i = blockIdx.x * 256 + threadIdx.x;
  int stride = gridDim.x * 256;
  for (; i < n4; i += stride) {
    float4 v = reinterpret_cast<const float4*>(in)[i];
    ushort4 o;
    o.x = f2b(v.x); o.y = f2b(v.y); o.z = f2b(v.z); o.w = f2b(v.w);
    int ci = i & 511;
    int t = ci & 7;
    int ci2 = (ci & ~7) | ((t & 3) << 1) | (t >> 2);
    reinterpret_cast<ushort4*>(out)[(i & ~511) | ci2] = o;
  }
}

// in: (K,N) fp32 row-major -> out: (N,K) bf16 row-major with K-dim interleave perm
__global__ __launch_bounds__(256) void k_transpose(const float* __restrict__ in,
                                                   unsigned short* __restrict__ out,
                                                   int K, int N) {
  __shared__ float tile[32][33];
  int n0 = blockIdx.x * 32, k0 = blockIdx.y * 32;
  int tx = threadIdx.x, ty = threadIdx.y;
#pragma unroll
  for (int j = 0; j < 32; j += 8)
    tile[ty + j][tx] = in[(size_t)(k0 + ty + j) * N + n0 + tx];
  __syncthreads();
  int kp = ((tx >> 2) & 3) * 8 + (tx & 3) + ((tx >> 4) << 2);
#pragma unroll
  for (int j = 0; j < 32; j += 8)
    out[(size_t)(n0 + ty + j) * K + k0 + kp] = f2b(tile[tx][ty + j]);
}

// C = A(M x K) * Bt(N x K)^T, bf16 (K-dim pre-interleaved), 128x128 tile, 4 waves.
// T3/T4 pipeline: 3 LDS buffers, distance-2 gload_lds prefetch, counted
// s_waitcnt vmcnt(4) (never 0 mid-loop), ONE raw s_barrier per K-step.
template <int EPI>
__global__ __launch_bounds__(256) void k_gemm(
    const unsigned short* __restrict__ A, const unsigned short* __restrict__ Bt,
    float* __restrict__ outF, unsigned short* __restrict__ qws,
    unsigned short* __restrict__ kws, unsigned short* __restrict__ vTws,
    float* __restrict__ koutF, float* __restrict__ voutF,
    const float* __restrict__ cosT, const float* __restrict__ sinT) {
  __shared__ __align__(16) unsigned short lA[3][128 * 32];
  __shared__ __align__(16) unsigned short lB[3][128 * 32];
  const int rowbase = blockIdx.x * 128;
  const int colbase = blockIdx.y * 128;
  const int t = threadIdx.x;
  const int wid = t >> 6, lane = t & 63;
  const int g = lane >> 4, c = lane & 15;
  const int wrow = (wid >> 1) * 64, wcol = (wid & 1) * 64;

  const int rloc = lane >> 2, sslot = lane & 3;

  f32x4 acc[4][4] = {};

  const int NT = KDIM / 32;  // 64

  auto STAGE = [&](int buf, int kt) {
    const int kbase = kt * 32;
#pragma unroll
    for (int j = 0; j < 2; ++j) {
      int r = wid * 32 + j * 16 + rloc;
      int gch = sslot ^ ((r >> 1) & 3);
      gload16(A + (size_t)(rowbase + r) * KDIM + kbase + gch * 8,
              &lA[buf][(wid * 32 + j * 16) * 32]);
      gload16(Bt + (size_t)(colbase + r) * KDIM + kbase + gch * 8,
              &lB[buf][(wid * 32 + j * 16) * 32]);
    }
  };

  // prologue: tiles 0,1 in flight
  STAGE(0, 0);
  STAGE(1, 1);

  int cur = 0;
  for (int kt = 0; kt < NT; ++kt) {
    // tile kt landed (own-wave); tile kt+1 may stay in flight
    if (kt < NT - 1) {
      asm volatile("s_waitcnt vmcnt(4)" ::: "memory");
    } else {
      asm volatile("s_waitcnt vmcnt(0)" ::: "memory");
    }
    __builtin_amdgcn_sched_barrier(0);
    __builtin_amdgcn_s_barrier();  // all waves' tile-kt loads landed; prior reads of buf[(kt+2)%3] done
    if (kt + 2 < NT) {
      int nbuf = cur + 2 >= 3 ? cur - 1 : cur + 2;
      STAGE(nbuf, kt + 2);
    }

    const unsigned short* la = lA[cur];
    const unsigned short* lb = lB[cur];
    bf16x8 af[4], bfm[4];
#pragma unroll
    for (int m = 0; m < 4; ++m) {
      int r = wrow + m * 16 + c;
      int slot = g ^ ((r >> 1) & 3);
      af[m] = *reinterpret_cast<const bf16x8*>(la + r * 32 + slot * 8);
    }
#pragma unroll
    for (int n = 0; n < 4; ++n) {
      int r = wcol + n * 16 + c;
      int slot = g ^ ((r >> 1) & 3);
      bfm[n] = *reinterpret_cast<const bf16x8*>(lb + r * 32 + slot * 8);
    }
    asm volatile("s_waitcnt lgkmcnt(0)" ::: "memory");
    __builtin_amdgcn_sched_barrier(0);
    __builtin_amdgcn_s_setprio(1);
#pragma unroll
    for (int m = 0; m < 4; ++m)
#pragma unroll
      for (int n = 0; n < 4; ++n)
        acc[m][n] = __builtin_amdgcn_mfma_f32_16x16x32_bf16(af[m], bfm[n], acc[m][n], 0, 0, 0);
    __builtin_amdgcn_s_setprio(0);
    cur = (cur == 2) ? 0 : cur + 1;
  }

  if (EPI == 0) {
#pragma unroll
    for (int m = 0; m < 4; ++m)
#pragma unroll
      for (int n = 0; n < 4; ++n)
#pragma unroll
        for (int i = 0; i < 4; ++i) {
          int R = rowbase + wrow + m * 16 + g * 4 + i;
          int Cc = colbase + wcol + n * 16 + c;
          outF[(size_t)R * 2048 + Cc] = acc[m][n][i];
        }
  } else {
#pragma unroll
    for (int m = 0; m < 4; ++m) {
#pragma unroll
      for (int n = 0; n < 4; ++n) {
#pragma unroll
        for (int i = 0; i < 4; ++i) {
          float val = acc[m][n][i];
          float partner = __shfl_xor(val, 1, 64);
          int R = rowbase + wrow + m * 16 + g * 4 + i;
          int Cc = colbase + wcol + n * 16 + c;
          int b = R >> 11, s = R & 2047;
          int d = Cc & 127;
          int j = d >> 1;
          float cs = cosT[s * 64 + j], sn = sinT[s * 64 + j];
          float ro = ((d & 1) == 0) ? (val * cs - partner * sn)
                                    : (partner * sn + val * cs);
          if (Cc < 2048) {
            int h = Cc >> 7;
            qws[((size_t)(b * HH + h) * SS + s) * DD + d] = f2b(ro);
          } else if (Cc < 2560) {
            int kvh = (Cc - 2048) >> 7;
            size_t idx = ((size_t)(b * KVH + kvh) * SS + s) * DD + d;
            koutF[idx] = ro;
            // kws: d pre-interleaved within 16-groups for k_attn's A-frag staging
            int d16 = d & 15;
            int dp = (d & ~15) | (d16 & 3) | ((d16 & 4) << 1) | ((d16 & 8) >> 1);
            kws[((size_t)(b * KVH + kvh) * SS + s) * DD + dp] = f2b(ro);
          } else {
            int kvh = (Cc - 2560) >> 7;
            size_t idx = ((size_t)(b * KVH + kvh) * SS + s) * DD + d;
            voutF[idx] = val;
            // vTws: s pre-interleaved within 16-groups for k_attn's A-frag staging
            int s16 = s & 15;
            int sp = (s & ~15) | (s16 & 3) | ((s16 & 4) << 1) | ((s16 & 8) >> 1);
            vTws[((size_t)(b * KVH + kvh) * DD + d) * SS + sp] = f2b(val);
          }
        }
      }
    }
  }
}

// LPT job table: 24 jobs/head sorted by tile count desc.
// full chunks c=0..7 (NT=2c+2); split chunks c=8..15 as two KV-halves (NT=c+1 each).
__constant__ int JC[24] = {7,15,15,14,14,6,13,13,12,12,5,11,11,10,10,4,9,9,8,8,3,2,1,0};
__constant__ int JP[24] = {0,0,1, 0,1, 0,0,1, 0,1, 0,0,1, 0,1, 0,0,1, 0,1, 0,0,0,0};

// Flash attention, 32x32 MFMA, double-swapped operands (unchanged from R7).
__global__ __launch_bounds__(256, 2) void k_attn(const unsigned short* __restrict__ qws,
                                                 const unsigned short* __restrict__ kws,
                                                 const unsigned short* __restrict__ vT,
                                                 unsigned short* __restrict__ aows,
                                                 unsigned short* __restrict__ pO,
                                                 float* __restrict__ pml) {
  __shared__ __align__(16) char lds[2][32768];  // per buf: K 16KB | V 16KB
  const int tid = threadIdx.x;
  const int lane = tid & 63;
  const int w = tid >> 6;
  const int lq = lane & 31;   // this lane's q-column
  const int hi = lane >> 5;   // k-parity half

  const int bid = blockIdx.x;
  const int j = bid >> 5;                           // job id (LPT order)
  const int y = bid & 31;
  const int head = 4 * (y & 7) + ((y >> 3) & 3);    // one (b,kv) per XCD
  const int c = JC[j];
  const int part = JP[j];
  const bool split = (c >= 8);
  const int tstart = split ? (part ? (c + 1) : 0) : 0;
  const int tend = split ? (part ? (2 * c + 2) : (c + 1)) : (2 * c + 2);

  const int b = head >> 4, h = head & 15;
  const int kv = h >> 2;
  const int q0w = c * 128 + w * 32;
  const int qg = q0w + lq;
  const float cl2 = 0.12751743f;  // (1/sqrt(128)) * log2(e)

  const unsigned short* qp = qws + ((size_t)(b * HH + h) * SS + qg) * DD;
  bf16x8 qf[8];
#pragma unroll
  for (int ks = 0; ks < 8; ++ks) {
    union { bf16x8 v8; bf16x4 v4[2]; } u;
    const unsigned short* p = qp + ks * 16 + hi * 4;
    u.v4[0] = *reinterpret_cast<const bf16x4*>(p);
    u.v4[1] = *reinterpret_cast<const bf16x4*>(p + 8);
    qf[ks] = u.v8;
  }

  const unsigned short* kbase = kws + (size_t)(b * KVH + kv) * SS * DD;
  const unsigned short* vbase = vT + (size_t)(b * KVH + kv) * DD * SS;

  // per-lane staging sources: wave w handles instrs i = w + 4*j2, j2=0..3
  const unsigned short* kSrc[4];
  const unsigned short* vSrc[4];
  int ldsOff[4];
#pragma unroll
  for (int j2 = 0; j2 < 4; ++j2) {
    int i = w + 4 * j2;
    int ks = i >> 1, half = i & 1;
    kSrc[j2] = kbase + (size_t)(half * 32 + (lane >> 1)) * DD + ks * 16 + (lane & 1) * 8;
    int kkv = i >> 2, d0v = i & 3;
    vSrc[j2] = vbase + (size_t)(d0v * 32 + (lane >> 1)) * SS + kkv * 16 + (lane & 1) * 8;
    ldsOff[j2] = i * 1024;
  }

  auto STAGE = [&](int t, int buf) {
    char* lK = lds[buf];
    char* lV = lds[buf] + 16384;
#pragma unroll
    for (int j2 = 0; j2 < 4; ++j2) {
      gload16(kSrc[j2] + (size_t)t * 64 * DD, (unsigned short*)(lK + ldsOff[j2]));
      gload16(vSrc[j2] + (size_t)t * 64, (unsigned short*)(lV + ldsOff[j2]));
    }
  };

  f32x16 o[4] = {};
  float mrow = -1e30f, lrow = 0.f;

  // prologue: two tiles in flight
  STAGE(tstart, 0);
  STAGE(tstart + 1, 1);
  asm volatile("s_waitcnt vmcnt(8)" ::: "memory");
  __builtin_amdgcn_sched_barrier(0);
  __builtin_amdgcn_s_barrier();

  for (int t = tstart; t < tend; ++t) {
    const int cur = (t - tstart) & 1;

    if (t * 64 <= q0w + 31) {  // wave has live rows in this tile
      const char* lK = lds[cur];
      const char* lV = lds[cur] + 16384;
      const bool full2 = (t * 64 + 32 <= q0w + 31);

      f32x16 s0 = {}, s1 = {};
      __builtin_amdgcn_s_setprio(1);
#pragma unroll
      for (int ks = 0; ks < 8; ++ks) {
        int off = ks * 2048 + lq * 32 + hi * 16;
        s0 = __builtin_amdgcn_mfma_f32_32x32x16_bf16(ldT(lK, off), qf[ks], s0, 0, 0, 0);
      }
      if (full2) {
#pragma unroll
        for (int ks = 0; ks < 8; ++ks) {
          int off = ks * 2048 + 1024 + lq * 32 + hi * 16;
          s1 = __builtin_amdgcn_mfma_f32_32x32x16_bf16(ldT(lK, off), qf[ks], s1, 0, 0, 0);
        }
      }
      __builtin_amdgcn_s_setprio(0);

      // softmax (log2 domain); k = t*64 + half*32 + (r&3)+8*(r>>2)+4*hi
      const int kq = t * 64 + 4 * hi - qg;
      float p[32];
      float rowmax = -1e30f;
      const bool m0 = (t * 64 + 31) > q0w;
#pragma unroll
      for (int r = 0; r < 16; ++r) {
        float v = s0[r] * cl2;
        if (m0) {
          int kl = (r & 3) + 8 * (r >> 2);
          if (kq + kl > 0) v = -1e30f;
        }
        p[r] = v;
        rowmax = fmaxf(rowmax, v);
      }
      if (full2) {
        const bool m1 = (t * 64 + 63) > q0w;
#pragma unroll
        for (int r = 0; r < 16; ++r) {
          float v = s1[r] * cl2;
          if (m1) {
            int kl = 32 + (r & 3) + 8 * (r >> 2);
            if (kq + kl > 0) v = -1e30f;
          }
          p[16 + r] = v;
          rowmax = fmaxf(rowmax, v);
        }
      }
      rowmax = fmaxf(rowmax, __shfl_xor(rowmax, 32, 64));

      if (__any(rowmax > mrow + 8.f)) {  // T13 defer-max
        float mnew = fmaxf(mrow, rowmax);
        float fac = exp2f(mrow - mnew);
        mrow = mnew;
        lrow *= fac;
#pragma unroll
        for (int d0 = 0; d0 < 4; ++d0)
#pragma unroll
          for (int r = 0; r < 16; ++r) o[d0][r] *= fac;
      }

      float rsum = 0.f;
#pragma unroll
      for (int e = 0; e < 16; ++e) { p[e] = exp2f(p[e] - mrow); rsum += p[e]; }
      if (full2) {
#pragma unroll
        for (int e = 16; e < 32; ++e) { p[e] = exp2f(p[e] - mrow); rsum += p[e]; }
      }
      rsum += __shfl_xor(rsum, 32, 64);
      lrow += rsum;

      bf16x8 pf[4];
#pragma unroll
      for (int s4 = 0; s4 < 2; ++s4) {
        union { bf16x8 v; unsigned u[4]; } pu;
        int base = s4 * 8;
#pragma unroll
        for (int jj = 0; jj < 4; ++jj)
          pu.u[jj] = cvtpk_bf16(p[base + 2 * jj], p[base + 2 * jj + 1]);
        pf[s4] = pu.v;
      }
      if (full2) {
#pragma unroll
        for (int s4 = 2; s4 < 4; ++s4) {
          union { bf16x8 v; unsigned u[4]; } pu;
          int base = 16 + (s4 - 2) * 8;
#pragma unroll
          for (int jj = 0; jj < 4; ++jj)
            pu.u[jj] = cvtpk_bf16(p[base + 2 * jj], p[base + 2 * jj + 1]);
          pf[s4] = pu.v;
        }
      }

      __builtin_amdgcn_s_setprio(1);
#pragma unroll
      for (int d0 = 0; d0 < 4; ++d0)
#pragma unroll
        for (int kk = 0; kk < 2; ++kk) {
          int off = (kk * 4 + d0) * 1024 + lq * 32 + hi * 16;
          o[d0] = __builtin_amdgcn_mfma_f32_32x32x16_bf16(ldT(lV, off), pf[kk], o[d0], 0, 0, 0);
        }
      if (full2) {
#pragma unroll
        for (int d0 = 0; d0 < 4; ++d0)
#pragma unroll
          for (int kk = 2; kk < 4; ++kk) {
            int off = (kk * 4 + d0) * 1024 + lq * 32 + hi * 16;
            o[d0] = __builtin_amdgcn_mfma_f32_32x32x16_bf16(ldT(lV, off), pf[kk], o[d0], 0, 0, 0);
          }
      }
      __builtin_amdgcn_s_setprio(0);
    }

    if (t + 1 < tend) {
      __builtin_amdgcn_s_barrier();           // all waves done reading buf[cur]
      if (t + 2 < tend) {
        STAGE(t + 2, cur);                    // overwrite buf[cur] (readers done)
        asm volatile("s_waitcnt vmcnt(8)" ::: "memory");  // t+1 landed; t+2 in flight
      } else {
        asm volatile("s_waitcnt vmcnt(0)" ::: "memory");  // t+1 landed
      }
      __builtin_amdgcn_sched_barrier(0);
      __builtin_amdgcn_s_barrier();           // publish t+1
    }
  }

  if (!split) {
    // normalize + store with K-dim interleave perm for GEMM2.
    float linv = 1.f / lrow;
    unsigned short* op = aows + ((size_t)(b * SS + qg)) * 2048 + h * 128;
#pragma unroll
    for (int d0 = 0; d0 < 4; ++d0)
#pragma unroll
      for (int rq = 0; rq < 4; ++rq) {
        unsigned w0 = cvtpk_bf16(o[d0][rq * 4 + 0] * linv, o[d0][rq * 4 + 1] * linv);
        unsigned w1 = cvtpk_bf16(o[d0][rq * 4 + 2] * linv, o[d0][rq * 4 + 3] * linv);
        int2 st2; st2.x = (int)w0; st2.y = (int)w1;
        int pos = 8 * ((2 * rq + hi) & 3) + 4 * (rq >> 1);
        *reinterpret_cast<int2*>(op + d0 * 32 + pos) = st2;
      }
  } else {
    // store unnormalized partial (plain d layout) + m,l
    int c8 = c - 8;
    int row = qg - c * 128;
    unsigned short* op = pO + ((((size_t)(head * 8 + c8) * 2 + part) * 128) + row) * 128;
#pragma unroll
    for (int d0 = 0; d0 < 4; ++d0)
#pragma unroll
      for (int rq = 0; rq < 4; ++rq) {
        unsigned w0 = cvtpk_bf16(o[d0][rq * 4 + 0], o[d0][rq * 4 + 1]);
        unsigned w1 = cvtpk_bf16(o[d0][rq * 4 + 2], o[d0][rq * 4 + 3]);
        int2 st2; st2.x = (int)w0; st2.y = (int)w1;
        *reinterpret_cast<int2*>(op + d0 * 32 + rq * 8 + hi * 4) = st2;
      }
    if (hi == 0) {
      int mlbase = (((head * 8 + c8) * 2 + part) * 2) * 128 + row;
      pml[mlbase] = mrow;
      pml[mlbase + 128] = lrow;
    }
  }
}

// Combine two KV-half partials for chunks 8..15 and write aows (perm'd bf16).
__global__ __launch_bounds__(256) void k_combine(const unsigned short* __restrict__ pO,
                                                 const float* __restrict__ pml,
                                                 unsigned short* __restrict__ aows) {
  int tid = blockIdx.x * 256 + threadIdx.x;  // 524288 total
  int rg = tid >> 4;
  int d8 = tid & 15;
  int head = rg >> 10;
  int rem = rg & 1023;
  int c8 = rem >> 7;
  int row = rem & 127;
  int base2 = (head * 8 + c8) * 2;

  float m1 = pml[((base2 + 0) * 2 + 0) * 128 + row];
  float l1 = pml[((base2 + 0) * 2 + 1) * 128 + row];
  float m2 = pml[((base2 + 1) * 2 + 0) * 128 + row];
  float l2 = pml[((base2 + 1) * 2 + 1) * 128 + row];
  float m = fmaxf(m1, m2);
  float w1 = exp2f(m1 - m), w2 = exp2f(m2 - m);
  float inv = 1.f / (w1 * l1 + w2 * l2);

  const unsigned short* o1 = pO + (((size_t)(base2 + 0) * 128 + row) * 128) + d8 * 8;
  const unsigned short* o2 = pO + (((size_t)(base2 + 1) * 128 + row) * 128) + d8 * 8;
  union { int4 q; unsigned short us[8]; } ua, ub;
  ua.q = *reinterpret_cast<const int4*>(o1);
  ub.q = *reinterpret_cast<const int4*>(o2);
  float out[8];
#pragma unroll
  for (int e = 0; e < 8; ++e)
    out[e] = (w1 * b2f(ua.us[e]) + w2 * b2f(ub.us[e])) * inv;

  int b = head >> 4, h = head & 15;
  int s = (c8 + 8) * 128 + row;
  unsigned short* dst = aows + ((size_t)(b * SS + s)) * 2048 + h * 128;
  int d = d8 * 8;
  int dbase = d & ~31;
#pragma unroll
  for (int jj = 0; jj < 2; ++jj) {
    int t = ((d >> 2) + jj) & 7;
    int pos = ((t & 3) << 3) + ((t >> 2) << 2);
    unsigned wa = cvtpk_bf16(out[jj * 4 + 0], out[jj * 4 + 1]);
    unsigned wb = cvtpk_bf16(out[jj * 4 + 2], out[jj * 4 + 3]);
    int2 st2; st2.x = (int)wa; st2.y = (int)wb;
    *reinterpret_cast<int2*>(dst + dbase + pos) = st2;
  }
}

extern "C" void kernel_launch(void* const* d_in, const int* in_sizes, int n_in,
                              void* d_out, int out_size, void* d_ws, size_t ws_size,
                              hipStream_t stream) {
  (void)in_sizes; (void)n_in; (void)out_size; (void)ws_size;
  const float* x  = (const float*)d_in[0];
  const float* fc = (const float*)d_in[1];
  const float* fs = (const float*)d_in[2];
  const float* wq = (const float*)d_in[3];
  const float* wk = (const float*)d_in[4];
  const float* wv = (const float*)d_in[5];
  const float* wo = (const float*)d_in[6];
  float* out = (float*)d_out;
  float* koutF = out + (size_t)BB * SS * HIDD;                  // (B,KV,S,D)
  float* voutF = koutF + (size_t)BB * KVH * SS * DD;            // (B,KV,S,D)

  unsigned short* wcatT = (unsigned short*)d_ws;                // (3072, 2048)
  unsigned short* woT   = wcatT + (size_t)3072 * 2048;          // (2048, 2048)
  unsigned short* xbf   = woT + (size_t)2048 * 2048;            // (4096, 2048)
  unsigned short* qws   = xbf + (size_t)4096 * 2048;            // (B,H,S,D)
  unsigned short* kws   = qws + (size_t)BB * HH * SS * DD;      // (B,KV,S,D) d-interleaved
  unsigned short* vTws  = kws + (size_t)BB * KVH * SS * DD;     // (B,KV,D,S) s-interleaved
  unsigned short* aows  = vTws + (size_t)BB * KVH * DD * SS;    // (B*S, H*D)

  // partials alias regions dead after k_gemm<1>:
  unsigned short* pO = xbf;            // 32*8*2*128*128 shorts = xbf size exactly
  float* pml = (float*)wcatT;          // 131072 floats << wcatT size

  k_convert<<<2048, 256, 0, stream>>>(x, xbf, (int)((size_t)4096 * 2048 / 4));
  dim3 tb(32, 8);
  k_transpose<<<dim3(64, 64), tb, 0, stream>>>(wq, wcatT, 2048, 2048);
  k_transpose<<<dim3(16, 64), tb, 0, stream>>>(wk, wcatT + (size_t)2048 * 2048, 2048, 512);
  k_transpose<<<dim3(16, 64), tb, 0, stream>>>(wv, wcatT + (size_t)2560 * 2048, 2048, 512);
  k_transpose<<<dim3(64, 64), tb, 0, stream>>>(wo, woT, 2048, 2048);

  k_gemm<1><<<dim3(32, 24), 256, 0, stream>>>(xbf, wcatT, nullptr, qws, kws, vTws,
                                              koutF, voutF, fc, fs);
  k_attn<<<768, 256, 0, stream>>>(qws, kws, vTws, aows, pO, pml);
  k_combine<<<2048, 256, 0, stream>>>(pO, pml, aows);
  k_gemm<0><<<dim3(32, 16), 256, 0, stream>>>(aows, woT, out, nullptr, nullptr, nullptr,
                                              nullptr, nullptr, nullptr, nullptr);
}

// Round 9
// 238.867 us; speedup vs baseline: 1.1777x; 1.0686x over previous
//
#include <hip/hip_runtime.h>
#include <stdint.h>

// Problem constants
#define BB 2
#define SS 2048
#define HIDD 2048
#define HH 16
#define KVH 4
#define DD 128
#define KDIM 2048

typedef short bf16x4 __attribute__((ext_vector_type(4)));
typedef short bf16x8 __attribute__((ext_vector_type(8)));
typedef float f32x4 __attribute__((ext_vector_type(4)));
typedef float f32x16 __attribute__((ext_vector_type(16)));

__device__ __forceinline__ unsigned short f2b(float f) {
  union { float f; unsigned u; } v; v.f = f;
  unsigned r = v.u + 0x7FFFu + ((v.u >> 16) & 1u);
  return (unsigned short)(r >> 16);
}

__device__ __forceinline__ float b2f(unsigned short u) {
  union { unsigned u; float f; } v; v.u = ((unsigned)u) << 16;
  return v.f;
}

__device__ __forceinline__ unsigned cvtpk_bf16(float a, float b) {
  unsigned r;
  asm("v_cvt_pk_bf16_f32 %0, %1, %2" : "=v"(r) : "v"(a), "v"(b));
  return r;
}

// async global->LDS, 16B per lane; LDS dest is wave-uniform base + lane*16
__device__ __forceinline__ void gload16(const unsigned short* g, unsigned short* l) {
  __builtin_amdgcn_global_load_lds(
      (const __attribute__((address_space(1))) unsigned int*)(g),
      (__attribute__((address_space(3))) unsigned int*)(l), 16, 0, 0);
}

// 16B LDS tile read
__device__ __forceinline__ bf16x8 ldT(const char* lds, int byteoff) {
  union { bf16x8 v; int4 q; } u;
  u.q = *reinterpret_cast<const int4*>(lds + byteoff);
  return u.v;
}

// A/B-fragment interleave within a 16-elem group: element x stored at
// pos16(x) = (x&3) | ((x&4)<<1) | ((x&8)>>1); then a contiguous 16B chunk
// (8 elems) holds x = base + {0,1,2,3,8,9,10,11} — the MFMA fragment order.

// K-dim interleave perm within 32-elem blocks (for 16x16x32 GEMM frags):
// perm(k32) = ((k32>>2)&3)*8 + (k32&3) + ((k32>>4)<<2)

__global__ __launch_bounds__(256) void k_convert(const float* __restrict__ in,
                                                 unsigned short* __restrict__ out, int n4) {
  int i = blockIdx.x * 256 + threadIdx.x;
  int stride = gridDim.x * 256;
  for (; i < n4; i += stride) {
    float4 v = reinterpret_cast<const float4*>(in)[i];
    ushort4 o;
    o.x = f2b(v.x); o.y = f2b(v.y); o.z = f2b(v.z); o.w = f2b(v.w);
    int ci = i & 511;
    int t = ci & 7;
    int ci2 = (ci & ~7) | ((t & 3) << 1) | (t >> 2);
    reinterpret_cast<ushort4*>(out)[(i & ~511) | ci2] = o;
  }
}

// in: (K,N) fp32 row-major -> out: (N,K) bf16 row-major with K-dim interleave perm
__global__ __launch_bounds__(256) void k_transpose(const float* __restrict__ in,
                                                   unsigned short* __restrict__ out,
                                                   int K, int N) {
  __shared__ float tile[32][33];
  int n0 = blockIdx.x * 32, k0 = blockIdx.y * 32;
  int tx = threadIdx.x, ty = threadIdx.y;
#pragma unroll
  for (int j = 0; j < 32; j += 8)
    tile[ty + j][tx] = in[(size_t)(k0 + ty + j) * N + n0 + tx];
  __syncthreads();
  int kp = ((tx >> 2) & 3) * 8 + (tx & 3) + ((tx >> 4) << 2);
#pragma unroll
  for (int j = 0; j < 32; j += 8)
    out[(size_t)(n0 + ty + j) * K + k0 + kp] = f2b(tile[tx][ty + j]);
}

// C = A(M x K) * Bt(N x K)^T, bf16 (K-dim pre-interleaved), 128x128 tile, 4 waves.
// T3/T4 pipeline: 3 LDS buffers, distance-2 gload_lds prefetch, counted
// s_waitcnt vmcnt(4), ONE raw s_barrier per K-step. Step body order:
// reads -> stage -> MFMA (compiler fine-grained lgkmcnt; no order pinning, m141)
// -> trailing lgkmcnt(0) as the WAR guard before the next barrier.
template <int EPI>
__global__ __launch_bounds__(256) void k_gemm(
    const unsigned short* __restrict__ A, const unsigned short* __restrict__ Bt,
    float* __restrict__ outF, unsigned short* __restrict__ qws,
    unsigned short* __restrict__ kws, unsigned short* __restrict__ vTws,
    float* __restrict__ koutF, float* __restrict__ voutF,
    const float* __restrict__ cosT, const float* __restrict__ sinT) {
  __shared__ __align__(16) unsigned short lA[3][128 * 32];
  __shared__ __align__(16) unsigned short lB[3][128 * 32];
  const int rowbase = blockIdx.x * 128;
  const int colbase = blockIdx.y * 128;
  const int t = threadIdx.x;
  const int wid = t >> 6, lane = t & 63;
  const int g = lane >> 4, c = lane & 15;
  const int wrow = (wid >> 1) * 64, wcol = (wid & 1) * 64;

  const int rloc = lane >> 2, sslot = lane & 3;

  f32x4 acc[4][4] = {};

  const int NT = KDIM / 32;  // 64

  auto STAGE = [&](int buf, int kt) {
    const int kbase = kt * 32;
#pragma unroll
    for (int j = 0; j < 2; ++j) {
      int r = wid * 32 + j * 16 + rloc;
      int gch = sslot ^ ((r >> 1) & 3);
      gload16(A + (size_t)(rowbase + r) * KDIM + kbase + gch * 8,
              &lA[buf][(wid * 32 + j * 16) * 32]);
      gload16(Bt + (size_t)(colbase + r) * KDIM + kbase + gch * 8,
              &lB[buf][(wid * 32 + j * 16) * 32]);
    }
  };

  // prologue: tiles 0,1 in flight
  STAGE(0, 0);
  STAGE(1, 1);

  int cur = 0;
  for (int kt = 0; kt < NT; ++kt) {
    // tile kt landed (own-wave); tile kt+1 may stay in flight
    if (kt < NT - 1) {
      asm volatile("s_waitcnt vmcnt(4)" ::: "memory");
    } else {
      asm volatile("s_waitcnt vmcnt(0)" ::: "memory");
    }
    __builtin_amdgcn_sched_barrier(0);
    __builtin_amdgcn_s_barrier();  // all waves' tile-kt loads landed; prior reads of buf[(kt+2)%3] done

    const unsigned short* la = lA[cur];
    const unsigned short* lb = lB[cur];
    bf16x8 af[4], bfm[4];
#pragma unroll
    for (int m = 0; m < 4; ++m) {
      int r = wrow + m * 16 + c;
      int slot = g ^ ((r >> 1) & 3);
      af[m] = *reinterpret_cast<const bf16x8*>(la + r * 32 + slot * 8);
    }
#pragma unroll
    for (int n = 0; n < 4; ++n) {
      int r = wcol + n * 16 + c;
      int slot = g ^ ((r >> 1) & 3);
      bfm[n] = *reinterpret_cast<const bf16x8*>(lb + r * 32 + slot * 8);
    }

    if (kt + 2 < NT) {  // issue prefetch after reads; overlaps with MFMA below
      int nbuf = cur + 2 >= 3 ? cur - 1 : cur + 2;
      STAGE(nbuf, kt + 2);
    }

#pragma unroll
    for (int m = 0; m < 4; ++m)
#pragma unroll
      for (int n = 0; n < 4; ++n)
        acc[m][n] = __builtin_amdgcn_mfma_f32_16x16x32_bf16(af[m], bfm[n], acc[m][n], 0, 0, 0);

    // WAR guard: this wave's ds_reads of buf[cur] fully retired before the
    // next barrier (after which buf[cur] gets overwritten). Normally free.
    asm volatile("s_waitcnt lgkmcnt(0)" ::: "memory");
    cur = (cur == 2) ? 0 : cur + 1;
  }

  if (EPI == 0) {
#pragma unroll
    for (int m = 0; m < 4; ++m)
#pragma unroll
      for (int n = 0; n < 4; ++n)
#pragma unroll
        for (int i = 0; i < 4; ++i) {
          int R = rowbase + wrow + m * 16 + g * 4 + i;
          int Cc = colbase + wcol + n * 16 + c;
          outF[(size_t)R * 2048 + Cc] = acc[m][n][i];
        }
  } else {
#pragma unroll
    for (int m = 0; m < 4; ++m) {
#pragma unroll
      for (int n = 0; n < 4; ++n) {
#pragma unroll
        for (int i = 0; i < 4; ++i) {
          float val = acc[m][n][i];
          float partner = __shfl_xor(val, 1, 64);
          int R = rowbase + wrow + m * 16 + g * 4 + i;
          int Cc = colbase + wcol + n * 16 + c;
          int b = R >> 11, s = R & 2047;
          int d = Cc & 127;
          int j = d >> 1;
          float cs = cosT[s * 64 + j], sn = sinT[s * 64 + j];
          float ro = ((d & 1) == 0) ? (val * cs - partner * sn)
                                    : (partner * sn + val * cs);
          if (Cc < 2048) {
            int h = Cc >> 7;
            qws[((size_t)(b * HH + h) * SS + s) * DD + d] = f2b(ro);
          } else if (Cc < 2560) {
            int kvh = (Cc - 2048) >> 7;
            size_t idx = ((size_t)(b * KVH + kvh) * SS + s) * DD + d;
            koutF[idx] = ro;
            // kws: d pre-interleaved within 16-groups for k_attn's A-frag staging
            int d16 = d & 15;
            int dp = (d & ~15) | (d16 & 3) | ((d16 & 4) << 1) | ((d16 & 8) >> 1);
            kws[((size_t)(b * KVH + kvh) * SS + s) * DD + dp] = f2b(ro);
          } else {
            int kvh = (Cc - 2560) >> 7;
            size_t idx = ((size_t)(b * KVH + kvh) * SS + s) * DD + d;
            voutF[idx] = val;
            // vTws: s pre-interleaved within 16-groups for k_attn's A-frag staging
            int s16 = s & 15;
            int sp = (s & ~15) | (s16 & 3) | ((s16 & 4) << 1) | ((s16 & 8) >> 1);
            vTws[((size_t)(b * KVH + kvh) * DD + d) * SS + sp] = f2b(val);
          }
        }
      }
    }
  }
}

// LPT job table: 24 jobs/head sorted by tile count desc.
// full chunks c=0..7 (NT=2c+2); split chunks c=8..15 as two KV-halves (NT=c+1 each).
__constant__ int JC[24] = {7,15,15,14,14,6,13,13,12,12,5,11,11,10,10,4,9,9,8,8,3,2,1,0};
__constant__ int JP[24] = {0,0,1, 0,1, 0,0,1, 0,1, 0,0,1, 0,1, 0,0,1, 0,1, 0,0,0,0};

// Flash attention, 32x32 MFMA, double-swapped operands (unchanged from R7/R8).
__global__ __launch_bounds__(256, 2) void k_attn(const unsigned short* __restrict__ qws,
                                                 const unsigned short* __restrict__ kws,
                                                 const unsigned short* __restrict__ vT,
                                                 unsigned short* __restrict__ aows,
                                                 unsigned short* __restrict__ pO,
                                                 float* __restrict__ pml) {
  __shared__ __align__(16) char lds[2][32768];  // per buf: K 16KB | V 16KB
  const int tid = threadIdx.x;
  const int lane = tid & 63;
  const int w = tid >> 6;
  const int lq = lane & 31;   // this lane's q-column
  const int hi = lane >> 5;   // k-parity half

  const int bid = blockIdx.x;
  const int j = bid >> 5;                           // job id (LPT order)
  const int y = bid & 31;
  const int head = 4 * (y & 7) + ((y >> 3) & 3);    // one (b,kv) per XCD
  const int c = JC[j];
  const int part = JP[j];
  const bool split = (c >= 8);
  const int tstart = split ? (part ? (c + 1) : 0) : 0;
  const int tend = split ? (part ? (2 * c + 2) : (c + 1)) : (2 * c + 2);

  const int b = head >> 4, h = head & 15;
  const int kv = h >> 2;
  const int q0w = c * 128 + w * 32;
  const int qg = q0w + lq;
  const float cl2 = 0.12751743f;  // (1/sqrt(128)) * log2(e)

  const unsigned short* qp = qws + ((size_t)(b * HH + h) * SS + qg) * DD;
  bf16x8 qf[8];
#pragma unroll
  for (int ks = 0; ks < 8; ++ks) {
    union { bf16x8 v8; bf16x4 v4[2]; } u;
    const unsigned short* p = qp + ks * 16 + hi * 4;
    u.v4[0] = *reinterpret_cast<const bf16x4*>(p);
    u.v4[1] = *reinterpret_cast<const bf16x4*>(p + 8);
    qf[ks] = u.v8;
  }

  const unsigned short* kbase = kws + (size_t)(b * KVH + kv) * SS * DD;
  const unsigned short* vbase = vT + (size_t)(b * KVH + kv) * DD * SS;

  // per-lane staging sources: wave w handles instrs i = w + 4*j2, j2=0..3
  const unsigned short* kSrc[4];
  const unsigned short* vSrc[4];
  int ldsOff[4];
#pragma unroll
  for (int j2 = 0; j2 < 4; ++j2) {
    int i = w + 4 * j2;
    int ks = i >> 1, half = i & 1;
    kSrc[j2] = kbase + (size_t)(half * 32 + (lane >> 1)) * DD + ks * 16 + (lane & 1) * 8;
    int kkv = i >> 2, d0v = i & 3;
    vSrc[j2] = vbase + (size_t)(d0v * 32 + (lane >> 1)) * SS + kkv * 16 + (lane & 1) * 8;
    ldsOff[j2] = i * 1024;
  }

  auto STAGE = [&](int t, int buf) {
    char* lK = lds[buf];
    char* lV = lds[buf] + 16384;
#pragma unroll
    for (int j2 = 0; j2 < 4; ++j2) {
      gload16(kSrc[j2] + (size_t)t * 64 * DD, (unsigned short*)(lK + ldsOff[j2]));
      gload16(vSrc[j2] + (size_t)t * 64, (unsigned short*)(lV + ldsOff[j2]));
    }
  };

  f32x16 o[4] = {};
  float mrow = -1e30f, lrow = 0.f;

  // prologue: two tiles in flight
  STAGE(tstart, 0);
  STAGE(tstart + 1, 1);
  asm volatile("s_waitcnt vmcnt(8)" ::: "memory");
  __builtin_amdgcn_sched_barrier(0);
  __builtin_amdgcn_s_barrier();

  for (int t = tstart; t < tend; ++t) {
    const int cur = (t - tstart) & 1;

    if (t * 64 <= q0w + 31) {  // wave has live rows in this tile
      const char* lK = lds[cur];
      const char* lV = lds[cur] + 16384;
      const bool full2 = (t * 64 + 32 <= q0w + 31);

      f32x16 s0 = {}, s1 = {};
      __builtin_amdgcn_s_setprio(1);
#pragma unroll
      for (int ks = 0; ks < 8; ++ks) {
        int off = ks * 2048 + lq * 32 + hi * 16;
        s0 = __builtin_amdgcn_mfma_f32_32x32x16_bf16(ldT(lK, off), qf[ks], s0, 0, 0, 0);
      }
      if (full2) {
#pragma unroll
        for (int ks = 0; ks < 8; ++ks) {
          int off = ks * 2048 + 1024 + lq * 32 + hi * 16;
          s1 = __builtin_amdgcn_mfma_f32_32x32x16_bf16(ldT(lK, off), qf[ks], s1, 0, 0, 0);
        }
      }
      __builtin_amdgcn_s_setprio(0);

      // softmax (log2 domain); k = t*64 + half*32 + (r&3)+8*(r>>2)+4*hi
      const int kq = t * 64 + 4 * hi - qg;
      float p[32];
      float rowmax = -1e30f;
      const bool m0 = (t * 64 + 31) > q0w;
#pragma unroll
      for (int r = 0; r < 16; ++r) {
        float v = s0[r] * cl2;
        if (m0) {
          int kl = (r & 3) + 8 * (r >> 2);
          if (kq + kl > 0) v = -1e30f;
        }
        p[r] = v;
        rowmax = fmaxf(rowmax, v);
      }
      if (full2) {
        const bool m1 = (t * 64 + 63) > q0w;
#pragma unroll
        for (int r = 0; r < 16; ++r) {
          float v = s1[r] * cl2;
          if (m1) {
            int kl = 32 + (r & 3) + 8 * (r >> 2);
            if (kq + kl > 0) v = -1e30f;
          }
          p[16 + r] = v;
          rowmax = fmaxf(rowmax, v);
        }
      }
      rowmax = fmaxf(rowmax, __shfl_xor(rowmax, 32, 64));

      if (__any(rowmax > mrow + 8.f)) {  // T13 defer-max
        float mnew = fmaxf(mrow, rowmax);
        float fac = exp2f(mrow - mnew);
        mrow = mnew;
        lrow *= fac;
#pragma unroll
        for (int d0 = 0; d0 < 4; ++d0)
#pragma unroll
          for (int r = 0; r < 16; ++r) o[d0][r] *= fac;
      }

      float rsum = 0.f;
#pragma unroll
      for (int e = 0; e < 16; ++e) { p[e] = exp2f(p[e] - mrow); rsum += p[e]; }
      if (full2) {
#pragma unroll
        for (int e = 16; e < 32; ++e) { p[e] = exp2f(p[e] - mrow); rsum += p[e]; }
      }
      rsum += __shfl_xor(rsum, 32, 64);
      lrow += rsum;

      bf16x8 pf[4];
#pragma unroll
      for (int s4 = 0; s4 < 2; ++s4) {
        union { bf16x8 v; unsigned u[4]; } pu;
        int base = s4 * 8;
#pragma unroll
        for (int jj = 0; jj < 4; ++jj)
          pu.u[jj] = cvtpk_bf16(p[base + 2 * jj], p[base + 2 * jj + 1]);
        pf[s4] = pu.v;
      }
      if (full2) {
#pragma unroll
        for (int s4 = 2; s4 < 4; ++s4) {
          union { bf16x8 v; unsigned u[4]; } pu;
          int base = 16 + (s4 - 2) * 8;
#pragma unroll
          for (int jj = 0; jj < 4; ++jj)
            pu.u[jj] = cvtpk_bf16(p[base + 2 * jj], p[base + 2 * jj + 1]);
          pf[s4] = pu.v;
        }
      }

      __builtin_amdgcn_s_setprio(1);
#pragma unroll
      for (int d0 = 0; d0 < 4; ++d0)
#pragma unroll
        for (int kk = 0; kk < 2; ++kk) {
          int off = (kk * 4 + d0) * 1024 + lq * 32 + hi * 16;
          o[d0] = __builtin_amdgcn_mfma_f32_32x32x16_bf16(ldT(lV, off), pf[kk], o[d0], 0, 0, 0);
        }
      if (full2) {
#pragma unroll
        for (int d0 = 0; d0 < 4; ++d0)
#pragma unroll
          for (int kk = 2; kk < 4; ++kk) {
            int off = (kk * 4 + d0) * 1024 + lq * 32 + hi * 16;
            o[d0] = __builtin_amdgcn_mfma_f32_32x32x16_bf16(ldT(lV, off), pf[kk], o[d0], 0, 0, 0);
          }
      }
      __builtin_amdgcn_s_setprio(0);
    }

    if (t + 1 < tend) {
      __builtin_amdgcn_s_barrier();           // all waves done reading buf[cur]
      if (t + 2 < tend) {
        STAGE(t + 2, cur);                    // overwrite buf[cur] (readers done)
        asm volatile("s_waitcnt vmcnt(8)" ::: "memory");  // t+1 landed; t+2 in flight
      } else {
        asm volatile("s_waitcnt vmcnt(0)" ::: "memory");  // t+1 landed
      }
      __builtin_amdgcn_sched_barrier(0);
      __builtin_amdgcn_s_barrier();           // publish t+1
    }
  }

  if (!split) {
    // normalize + store with K-dim interleave perm for GEMM2.
    float linv = 1.f / lrow;
    unsigned short* op = aows + ((size_t)(b * SS + qg)) * 2048 + h * 128;
#pragma unroll
    for (int d0 = 0; d0 < 4; ++d0)
#pragma unroll
      for (int rq = 0; rq < 4; ++rq) {
        unsigned w0 = cvtpk_bf16(o[d0][rq * 4 + 0] * linv, o[d0][rq * 4 + 1] * linv);
        unsigned w1 = cvtpk_bf16(o[d0][rq * 4 + 2] * linv, o[d0][rq * 4 + 3] * linv);
        int2 st2; st2.x = (int)w0; st2.y = (int)w1;
        int pos = 8 * ((2 * rq + hi) & 3) + 4 * (rq >> 1);
        *reinterpret_cast<int2*>(op + d0 * 32 + pos) = st2;
      }
  } else {
    // store unnormalized partial (plain d layout) + m,l
    int c8 = c - 8;
    int row = qg - c * 128;
    unsigned short* op = pO + ((((size_t)(head * 8 + c8) * 2 + part) * 128) + row) * 128;
#pragma unroll
    for (int d0 = 0; d0 < 4; ++d0)
#pragma unroll
      for (int rq = 0; rq < 4; ++rq) {
        unsigned w0 = cvtpk_bf16(o[d0][rq * 4 + 0], o[d0][rq * 4 + 1]);
        unsigned w1 = cvtpk_bf16(o[d0][rq * 4 + 2], o[d0][rq * 4 + 3]);
        int2 st2; st2.x = (int)w0; st2.y = (int)w1;
        *reinterpret_cast<int2*>(op + d0 * 32 + rq * 8 + hi * 4) = st2;
      }
    if (hi == 0) {
      int mlbase = (((head * 8 + c8) * 2 + part) * 2) * 128 + row;
      pml[mlbase] = mrow;
      pml[mlbase + 128] = lrow;
    }
  }
}

// Combine two KV-half partials for chunks 8..15 and write aows (perm'd bf16).
__global__ __launch_bounds__(256) void k_combine(const unsigned short* __restrict__ pO,
                                                 const float* __restrict__ pml,
                                                 unsigned short* __restrict__ aows) {
  int tid = blockIdx.x * 256 + threadIdx.x;  // 524288 total
  int rg = tid >> 4;
  int d8 = tid & 15;
  int head = rg >> 10;
  int rem = rg & 1023;
  int c8 = rem >> 7;
  int row = rem & 127;
  int base2 = (head * 8 + c8) * 2;

  float m1 = pml[((base2 + 0) * 2 + 0) * 128 + row];
  float l1 = pml[((base2 + 0) * 2 + 1) * 128 + row];
  float m2 = pml[((base2 + 1) * 2 + 0) * 128 + row];
  float l2 = pml[((base2 + 1) * 2 + 1) * 128 + row];
  float m = fmaxf(m1, m2);
  float w1 = exp2f(m1 - m), w2 = exp2f(m2 - m);
  float inv = 1.f / (w1 * l1 + w2 * l2);

  const unsigned short* o1 = pO + (((size_t)(base2 + 0) * 128 + row) * 128) + d8 * 8;
  const unsigned short* o2 = pO + (((size_t)(base2 + 1) * 128 + row) * 128) + d8 * 8;
  union { int4 q; unsigned short us[8]; } ua, ub;
  ua.q = *reinterpret_cast<const int4*>(o1);
  ub.q = *reinterpret_cast<const int4*>(o2);
  float out[8];
#pragma unroll
  for (int e = 0; e < 8; ++e)
    out[e] = (w1 * b2f(ua.us[e]) + w2 * b2f(ub.us[e])) * inv;

  int b = head >> 4, h = head & 15;
  int s = (c8 + 8) * 128 + row;
  unsigned short* dst = aows + ((size_t)(b * SS + s)) * 2048 + h * 128;
  int d = d8 * 8;
  int dbase = d & ~31;
#pragma unroll
  for (int jj = 0; jj < 2; ++jj) {
    int t = ((d >> 2) + jj) & 7;
    int pos = ((t & 3) << 3) + ((t >> 2) << 2);
    unsigned wa = cvtpk_bf16(out[jj * 4 + 0], out[jj * 4 + 1]);
    unsigned wb = cvtpk_bf16(out[jj * 4 + 2], out[jj * 4 + 3]);
    int2 st2; st2.x = (int)wa; st2.y = (int)wb;
    *reinterpret_cast<int2*>(dst + dbase + pos) = st2;
  }
}

extern "C" void kernel_launch(void* const* d_in, const int* in_sizes, int n_in,
                              void* d_out, int out_size, void* d_ws, size_t ws_size,
                              hipStream_t stream) {
  (void)in_sizes; (void)n_in; (void)out_size; (void)ws_size;
  const float* x  = (const float*)d_in[0];
  const float* fc = (const float*)d_in[1];
  const float* fs = (const float*)d_in[2];
  const float* wq = (const float*)d_in[3];
  const float* wk = (const float*)d_in[4];
  const float* wv = (const float*)d_in[5];
  const float* wo = (const float*)d_in[6];
  float* out = (float*)d_out;
  float* koutF = out + (size_t)BB * SS * HIDD;                  // (B,KV,S,D)
  float* voutF = koutF + (size_t)BB * KVH * SS * DD;            // (B,KV,S,D)

  unsigned short* wcatT = (unsigned short*)d_ws;                // (3072, 2048)
  unsigned short* woT   = wcatT + (size_t)3072 * 2048;          // (2048, 2048)
  unsigned short* xbf   = woT + (size_t)2048 * 2048;            // (4096, 2048)
  unsigned short* qws   = xbf + (size_t)4096 * 2048;            // (B,H,S,D)
  unsigned short* kws   = qws + (size_t)BB * HH * SS * DD;      // (B,KV,S,D) d-interleaved
  unsigned short* vTws  = kws + (size_t)BB * KVH * SS * DD;     // (B,KV,D,S) s-interleaved
  unsigned short* aows  = vTws + (size_t)BB * KVH * DD * SS;    // (B*S, H*D)

  // partials alias regions dead after k_gemm<1>:
  unsigned short* pO = xbf;            // 32*8*2*128*128 shorts = xbf size exactly
  float* pml = (float*)wcatT;          // 131072 floats << wcatT size

  k_convert<<<2048, 256, 0, stream>>>(x, xbf, (int)((size_t)4096 * 2048 / 4));
  dim3 tb(32, 8);
  k_transpose<<<dim3(64, 64), tb, 0, stream>>>(wq, wcatT, 2048, 2048);
  k_transpose<<<dim3(16, 64), tb, 0, stream>>>(wk, wcatT + (size_t)2048 * 2048, 2048, 512);
  k_transpose<<<dim3(16, 64), tb, 0, stream>>>(wv, wcatT + (size_t)2560 * 2048, 2048, 512);
  k_transpose<<<dim3(64, 64), tb, 0, stream>>>(wo, woT, 2048, 2048);

  k_gemm<1><<<dim3(32, 24), 256, 0, stream>>>(xbf, wcatT, nullptr, qws, kws, vTws,
                                              koutF, voutF, fc, fs);
  k_attn<<<768, 256, 0, stream>>>(qws, kws, vTws, aows, pO, pml);
  k_combine<<<2048, 256, 0, stream>>>(pO, pml, aows);
  k_gemm<0><<<dim3(32, 16), 256, 0, stream>>>(aows, woT, out, nullptr, nullptr, nullptr,
                                              nullptr, nullptr, nullptr, nullptr);
}